// Round 3
// baseline (96.781 us; speedup 1.0000x reference)
//
#include <hip/hip_runtime.h>
#include <math.h>

#define HDIM 1024
#define BDIM 64
#define NDIM 512

// ---------------- K1: e[b][n] = adj ? exp(dot(K[row], Wk)) : 0 --------------
// grid 4096 blocks x 256 threads; each wave computes 2 rows (8 loads in flight).
__global__ __launch_bounds__(256) void k_scores(const float* __restrict__ Kmat,
                                                const float* __restrict__ Wk,
                                                const int* __restrict__ adj,
                                                float* __restrict__ e_out) {
    int wave = threadIdx.x >> 6;
    int lane = threadIdx.x & 63;
    int base = blockIdx.x * 8 + wave * 2;   // row index (b*512+n)

    const float4* wk4 = (const float4*)Wk;
    const float4* kp0 = (const float4*)(Kmat + (size_t)base * HDIM);
    const float4* kp1 = (const float4*)(Kmat + (size_t)(base + 1) * HDIM);

    float s0 = 0.f, s1 = 0.f;
#pragma unroll
    for (int i = 0; i < 4; ++i) {
        float4 wv = wk4[i * 64 + lane];
        float4 k0 = kp0[i * 64 + lane];
        float4 k1 = kp1[i * 64 + lane];
        s0 = fmaf(k0.x, wv.x, s0); s0 = fmaf(k0.y, wv.y, s0);
        s0 = fmaf(k0.z, wv.z, s0); s0 = fmaf(k0.w, wv.w, s0);
        s1 = fmaf(k1.x, wv.x, s1); s1 = fmaf(k1.y, wv.y, s1);
        s1 = fmaf(k1.z, wv.z, s1); s1 = fmaf(k1.w, wv.w, s1);
    }
#pragma unroll
    for (int off = 32; off; off >>= 1) {
        s0 += __shfl_xor(s0, off);
        s1 += __shfl_xor(s1, off);
    }
    if (lane == 0) {
        e_out[base]     = adj[base]     ? expf(s0) : 0.f;
        e_out[base + 1] = adj[base + 1] ? expf(s1) : 0.f;
    }
}

// ---------------- K2: p0/p1[nc][b][h] = sum_{n in chunk} e*mask*V -----------
// grid 1024 blocks (b*16+nc), 256 threads. Chunk = 32 rows. e/masks are
// block-uniform per n -> scalar loads; V loads 8-deep independent per thread.
__global__ __launch_bounds__(256) void k_weightv(const float* __restrict__ V,
                                                 const float* __restrict__ e,
                                                 const int* __restrict__ smask,
                                                 const int* __restrict__ omask,
                                                 float* __restrict__ p0,
                                                 float* __restrict__ p1) {
    int b = blockIdx.x >> 4;
    int nc = blockIdx.x & 15;
    int tid = threadIdx.x;
    int gbase = b * 512 + nc * 32;

    const float4* vp = (const float4*)(V + (size_t)gbase * HDIM) + tid;
    float4 a0 = {0.f, 0.f, 0.f, 0.f};
    float4 a1 = {0.f, 0.f, 0.f, 0.f};
#pragma unroll 8
    for (int nn = 0; nn < 32; ++nn) {
        float ev = e[gbase + nn];                    // s_load (uniform)
        float es = smask[gbase + nn] ? ev : 0.f;
        float eo = omask[gbase + nn] ? ev : 0.f;
        float4 v = vp[nn * 256];
        a0.x = fmaf(es, v.x, a0.x); a0.y = fmaf(es, v.y, a0.y);
        a0.z = fmaf(es, v.z, a0.z); a0.w = fmaf(es, v.w, a0.w);
        a1.x = fmaf(eo, v.x, a1.x); a1.y = fmaf(eo, v.y, a1.y);
        a1.z = fmaf(eo, v.z, a1.z); a1.w = fmaf(eo, v.w, a1.w);
    }
    size_t o = ((size_t)(nc * 64 + b)) * HDIM + tid * 4;
    *(float4*)(p0 + o) = a0;
    *(float4*)(p1 + o) = a1;
}

// ---------------- K3: denom per b -> w_out = e/sum, inv[b] ------------------
// grid 64 blocks x 512 threads.
__global__ __launch_bounds__(512) void k_denom(const float* __restrict__ e,
                                               float* __restrict__ w_out,
                                               float* __restrict__ invArr) {
    __shared__ float red[8];
    int b = blockIdx.x;
    int tid = threadIdx.x;
    int wave = tid >> 6, lane = tid & 63;

    float ev = e[b * 512 + tid];
    float t = ev;
#pragma unroll
    for (int off = 32; off; off >>= 1) t += __shfl_xor(t, off);
    if (lane == 0) red[wave] = t;
    __syncthreads();
    float tot = red[0];
#pragma unroll
    for (int i = 1; i < 8; ++i) tot += red[i];
    float inv = 1.f / tot;
    w_out[b * 512 + tid] = ev * inv;
    if (tid == 0) invArr[b] = inv;
}

// ---------------- K4: u = inv[b] * sum_nc p -------------------------------
// grid 128 blocks (b*2+arr) x 256 threads (thread = f4 slot over 1024 h).
__global__ __launch_bounds__(256) void k_redu(const float* __restrict__ p0,
                                              const float* __restrict__ p1,
                                              const float* __restrict__ invArr,
                                              float* __restrict__ u0,
                                              float* __restrict__ u1) {
    int b = blockIdx.x >> 1;
    int arr = blockIdx.x & 1;
    int tid = threadIdx.x;
    const float* p = arr ? p1 : p0;
    float* u = arr ? u1 : u0;
    float inv = invArr[b];
    float4 a = {0.f, 0.f, 0.f, 0.f};
#pragma unroll
    for (int nc = 0; nc < 16; ++nc) {
        float4 v = *(const float4*)(p + ((size_t)(nc * 64 + b)) * HDIM + tid * 4);
        a.x += v.x; a.y += v.y; a.z += v.z; a.w += v.w;
    }
    a.x *= inv; a.y *= inv; a.z *= inv; a.w *= inv;
    *(float4*)(u + (size_t)b * HDIM + tid * 4) = a;
}

// ---------------- K5: split-k GEMM partials: pOut[kc][h][b] -----------------
// out[b][h] = sum_k u0[b][k]*Wr0[h][k] + u1[b][k]*Wr1[h][k]
// grid 256 blocks (ht*16+kc) x 256 threads. lane=b, wave owns 16 h rows.
__global__ __launch_bounds__(256) void k_out(const float* __restrict__ u0,
                                             const float* __restrict__ u1,
                                             const float* __restrict__ Wr0,
                                             const float* __restrict__ Wr1,
                                             float* __restrict__ pOut) {
    __shared__ float lds[64 * 128];
    int tid = threadIdx.x;
    int ht = blockIdx.x >> 4;   // 0..15  (h tile of 64)
    int kc = blockIdx.x & 15;   // 0..15  (k chunk of 128, over [u0|u1])
    const float* usrc = (kc < 8) ? u0 : u1;
    const float* wsrc = (kc < 8) ? Wr0 : Wr1;
    int koff = (kc & 7) * 128;
    int h0 = ht * 64;

    // stage U[0:64][koff:koff+128] into LDS, swizzled: f4 col' = col ^ (row&7)
    {
        int c4 = tid & 31;
        int r2 = tid >> 5;
#pragma unroll
        for (int i = 0; i < 8; ++i) {
            int row = i * 8 + r2;
            float4 v = *(const float4*)(usrc + (size_t)row * HDIM + koff + c4 * 4);
            *(float4*)&lds[row * 128 + ((c4 ^ (row & 7)) << 2)] = v;
        }
    }
    __syncthreads();

    int b = tid & 63;
    int wu = __builtin_amdgcn_readfirstlane(tid >> 6);
    int hbase = h0 + wu * 16;
    const float* wrow = wsrc + (size_t)hbase * HDIM + koff;

    float acc[16];
#pragma unroll
    for (int j = 0; j < 16; ++j) acc[j] = 0.f;

#pragma unroll 4
    for (int k4 = 0; k4 < 32; ++k4) {
        float4 uv = *(float4*)&lds[b * 128 + ((k4 ^ (b & 7)) << 2)];
#pragma unroll
        for (int j = 0; j < 16; ++j) {
            float4 wv = *(const float4*)(wrow + (size_t)j * HDIM + k4 * 4);
            acc[j] = fmaf(uv.x, wv.x, acc[j]);
            acc[j] = fmaf(uv.y, wv.y, acc[j]);
            acc[j] = fmaf(uv.z, wv.z, acc[j]);
            acc[j] = fmaf(uv.w, wv.w, acc[j]);
        }
    }
#pragma unroll
    for (int j = 0; j < 16; ++j)
        pOut[((size_t)kc * HDIM + hbase + j) * 64 + b] = acc[j];
}

// ---------------- K6: reduce 16 k-chunks -> attn_sum[b][h] ------------------
// grid 256 blocks x 256 threads (4 h x 64 b per block).
__global__ __launch_bounds__(256) void k_redout(const float* __restrict__ pOut,
                                                float* __restrict__ out1) {
    int tid = threadIdx.x;
    int b = tid & 63;
    int h = blockIdx.x * 4 + (tid >> 6);
    float acc = 0.f;
#pragma unroll
    for (int kc = 0; kc < 16; ++kc)
        acc += pOut[((size_t)kc * HDIM + h) * 64 + b];
    out1[(size_t)b * HDIM + h] = acc;
}

extern "C" void kernel_launch(void* const* d_in, const int* in_sizes, int n_in,
                              void* d_out, int out_size, void* d_ws, size_t ws_size,
                              hipStream_t stream) {
    const float* Kmat  = (const float*)d_in[1];
    const float* V     = (const float*)d_in[2];
    const int*   adj   = (const int*)d_in[3];
    const int*   smask = (const int*)d_in[4];
    const int*   omask = (const int*)d_in[5];
    const float* Watt  = (const float*)d_in[6];
    const float* Wr0   = (const float*)d_in[8];
    const float* Wr1   = (const float*)d_in[9];
    float* out = (float*)d_out;
    float* ws  = (float*)d_ws;

    // ws layout (float offsets)
    float* e    = ws;                 //  64*512   = 32768
    float* inv  = ws + 32768;         //  64 (pad 128)
    float* p0   = ws + 32896;         //  16*64*1024 = 1048576
    float* p1   = ws + 1081472;       //  16*64*1024 = 1048576
    float* u0   = ws + 2130048;       //  64*1024 = 65536
    float* u1   = ws + 2195584;       //  64*1024 = 65536
    float* pOut = ws + 2261120;       //  16*1024*64 = 1048576
    const float* Wk = Watt + HDIM;    // second half of W_att

    k_scores <<<4096, 256, 0, stream>>>(Kmat, Wk, adj, e);
    k_weightv<<<1024, 256, 0, stream>>>(V, e, smask, omask, p0, p1);
    k_denom  <<<  64, 512, 0, stream>>>(e, out, inv);
    k_redu   <<< 128, 256, 0, stream>>>(p0, p1, inv, u0, u1);
    k_out    <<< 256, 256, 0, stream>>>(u0, u1, Wr0, Wr1, pOut);
    k_redout <<< 256, 256, 0, stream>>>(pOut, out + 32768);
}

// Round 4
// 95.018 us; speedup vs baseline: 1.0186x; 1.0186x over previous
//
#include <hip/hip_runtime.h>
#include <math.h>

#define HDIM 1024
#define BDIM 64
#define NDIM 512

// ---------------- K1: fused score+exp+mask+V-weighting (deep-MLP) -----------
// grid 1024 blocks (b*16+nc), 512 threads = 8 waves. Chunk = 32 n-rows.
// Phase 1: wave w computes rows 4w..4w+3 as 2 pairs with 8 float4 loads in
//          flight -> e = adj ? exp(s) : 0 into LDS (+ e_out global).
// Phase 2: 512 threads = 2 row-halves x 256 h-slots; 8-deep V load batches;
//          halves combined through LDS so partial count stays 16 per b.
__global__ __launch_bounds__(512) void k_fused(const float* __restrict__ Kmat,
                                               const float* __restrict__ V,
                                               const int* __restrict__ adj,
                                               const int* __restrict__ smask,
                                               const int* __restrict__ omask,
                                               const float* __restrict__ Wk,
                                               float* __restrict__ e_out,
                                               float* __restrict__ p0,
                                               float* __restrict__ p1) {
    __shared__ float2 eso[32];
    __shared__ int mA[32], mS[32], mO[32];
    __shared__ float4 comb[512];    // 8 KB combine buffer
    int b = blockIdx.x >> 4;
    int nc = blockIdx.x & 15;
    int tid = threadIdx.x;
    int wave = tid >> 6, lane = tid & 63;
    int gbase = b * 512 + nc * 32;

    if (tid < 32) {
        mA[tid] = adj[gbase + tid];
        mS[tid] = smask[gbase + tid];
        mO[tid] = omask[gbase + tid];
    }
    const float4* wk4 = (const float4*)Wk;
    float4 wk0 = wk4[lane], wk1 = wk4[64 + lane],
           wk2 = wk4[128 + lane], wk3 = wk4[192 + lane];
    __syncthreads();

    // ---- phase 1: 4 rows per wave, 2 pairs, 8 loads in flight per pair ----
    int r0 = wave * 4;
#pragma unroll
    for (int pp = 0; pp < 2; ++pp) {
        int row = r0 + pp * 2;
        const float4* kp0 = (const float4*)(Kmat + (size_t)(gbase + row) * HDIM);
        const float4* kp1 = (const float4*)(Kmat + (size_t)(gbase + row + 1) * HDIM);
        float4 a0 = kp0[lane],       a1 = kp0[64 + lane],
               a2 = kp0[128 + lane], a3 = kp0[192 + lane];
        float4 c0 = kp1[lane],       c1 = kp1[64 + lane],
               c2 = kp1[128 + lane], c3 = kp1[192 + lane];
        float s0 = 0.f, s1 = 0.f;
        s0 = fmaf(a0.x, wk0.x, s0); s0 = fmaf(a0.y, wk0.y, s0);
        s0 = fmaf(a0.z, wk0.z, s0); s0 = fmaf(a0.w, wk0.w, s0);
        s0 = fmaf(a1.x, wk1.x, s0); s0 = fmaf(a1.y, wk1.y, s0);
        s0 = fmaf(a1.z, wk1.z, s0); s0 = fmaf(a1.w, wk1.w, s0);
        s0 = fmaf(a2.x, wk2.x, s0); s0 = fmaf(a2.y, wk2.y, s0);
        s0 = fmaf(a2.z, wk2.z, s0); s0 = fmaf(a2.w, wk2.w, s0);
        s0 = fmaf(a3.x, wk3.x, s0); s0 = fmaf(a3.y, wk3.y, s0);
        s0 = fmaf(a3.z, wk3.z, s0); s0 = fmaf(a3.w, wk3.w, s0);
        s1 = fmaf(c0.x, wk0.x, s1); s1 = fmaf(c0.y, wk0.y, s1);
        s1 = fmaf(c0.z, wk0.z, s1); s1 = fmaf(c0.w, wk0.w, s1);
        s1 = fmaf(c1.x, wk1.x, s1); s1 = fmaf(c1.y, wk1.y, s1);
        s1 = fmaf(c1.z, wk1.z, s1); s1 = fmaf(c1.w, wk1.w, s1);
        s1 = fmaf(c2.x, wk2.x, s1); s1 = fmaf(c2.y, wk2.y, s1);
        s1 = fmaf(c2.z, wk2.z, s1); s1 = fmaf(c2.w, wk2.w, s1);
        s1 = fmaf(c3.x, wk3.x, s1); s1 = fmaf(c3.y, wk3.y, s1);
        s1 = fmaf(c3.z, wk3.z, s1); s1 = fmaf(c3.w, wk3.w, s1);
#pragma unroll
        for (int off = 32; off; off >>= 1) {
            s0 += __shfl_xor(s0, off);
            s1 += __shfl_xor(s1, off);
        }
        if (lane == 0) {
            float e0 = mA[row]     ? expf(s0) : 0.f;
            float e1 = mA[row + 1] ? expf(s1) : 0.f;
            e_out[gbase + row]     = e0;
            e_out[gbase + row + 1] = e1;
            eso[row]     = make_float2(mS[row]     ? e0 : 0.f, mO[row]     ? e0 : 0.f);
            eso[row + 1] = make_float2(mS[row + 1] ? e1 : 0.f, mO[row + 1] ? e1 : 0.f);
        }
    }
    __syncthreads();

    // ---- phase 2: half-threads x 16 rows each, 8-deep load batches --------
    int slot = tid & 255;
    int rbase = (tid >> 8) * 16;   // 0 or 16
    const float4* vp = (const float4*)(V + (size_t)(gbase + rbase) * HDIM) + slot;
    float4 acc0 = {0.f, 0.f, 0.f, 0.f};
    float4 acc1 = {0.f, 0.f, 0.f, 0.f};
#pragma unroll
    for (int bb = 0; bb < 2; ++bb) {
        float4 v0 = vp[(bb * 8 + 0) * 256];
        float4 v1 = vp[(bb * 8 + 1) * 256];
        float4 v2 = vp[(bb * 8 + 2) * 256];
        float4 v3 = vp[(bb * 8 + 3) * 256];
        float4 v4 = vp[(bb * 8 + 4) * 256];
        float4 v5 = vp[(bb * 8 + 5) * 256];
        float4 v6 = vp[(bb * 8 + 6) * 256];
        float4 v7 = vp[(bb * 8 + 7) * 256];
        float2 w0 = eso[rbase + bb * 8 + 0];
        float2 w1 = eso[rbase + bb * 8 + 1];
        float2 w2 = eso[rbase + bb * 8 + 2];
        float2 w3 = eso[rbase + bb * 8 + 3];
        float2 w4 = eso[rbase + bb * 8 + 4];
        float2 w5 = eso[rbase + bb * 8 + 5];
        float2 w6 = eso[rbase + bb * 8 + 6];
        float2 w7 = eso[rbase + bb * 8 + 7];
        acc0.x = fmaf(w0.x, v0.x, acc0.x); acc0.y = fmaf(w0.x, v0.y, acc0.y);
        acc0.z = fmaf(w0.x, v0.z, acc0.z); acc0.w = fmaf(w0.x, v0.w, acc0.w);
        acc1.x = fmaf(w0.y, v0.x, acc1.x); acc1.y = fmaf(w0.y, v0.y, acc1.y);
        acc1.z = fmaf(w0.y, v0.z, acc1.z); acc1.w = fmaf(w0.y, v0.w, acc1.w);
        acc0.x = fmaf(w1.x, v1.x, acc0.x); acc0.y = fmaf(w1.x, v1.y, acc0.y);
        acc0.z = fmaf(w1.x, v1.z, acc0.z); acc0.w = fmaf(w1.x, v1.w, acc0.w);
        acc1.x = fmaf(w1.y, v1.x, acc1.x); acc1.y = fmaf(w1.y, v1.y, acc1.y);
        acc1.z = fmaf(w1.y, v1.z, acc1.z); acc1.w = fmaf(w1.y, v1.w, acc1.w);
        acc0.x = fmaf(w2.x, v2.x, acc0.x); acc0.y = fmaf(w2.x, v2.y, acc0.y);
        acc0.z = fmaf(w2.x, v2.z, acc0.z); acc0.w = fmaf(w2.x, v2.w, acc0.w);
        acc1.x = fmaf(w2.y, v2.x, acc1.x); acc1.y = fmaf(w2.y, v2.y, acc1.y);
        acc1.z = fmaf(w2.y, v2.z, acc1.z); acc1.w = fmaf(w2.y, v2.w, acc1.w);
        acc0.x = fmaf(w3.x, v3.x, acc0.x); acc0.y = fmaf(w3.x, v3.y, acc0.y);
        acc0.z = fmaf(w3.x, v3.z, acc0.z); acc0.w = fmaf(w3.x, v3.w, acc0.w);
        acc1.x = fmaf(w3.y, v3.x, acc1.x); acc1.y = fmaf(w3.y, v3.y, acc1.y);
        acc1.z = fmaf(w3.y, v3.z, acc1.z); acc1.w = fmaf(w3.y, v3.w, acc1.w);
        acc0.x = fmaf(w4.x, v4.x, acc0.x); acc0.y = fmaf(w4.x, v4.y, acc0.y);
        acc0.z = fmaf(w4.x, v4.z, acc0.z); acc0.w = fmaf(w4.x, v4.w, acc0.w);
        acc1.x = fmaf(w4.y, v4.x, acc1.x); acc1.y = fmaf(w4.y, v4.y, acc1.y);
        acc1.z = fmaf(w4.y, v4.z, acc1.z); acc1.w = fmaf(w4.y, v4.w, acc1.w);
        acc0.x = fmaf(w5.x, v5.x, acc0.x); acc0.y = fmaf(w5.x, v5.y, acc0.y);
        acc0.z = fmaf(w5.x, v5.z, acc0.z); acc0.w = fmaf(w5.x, v5.w, acc0.w);
        acc1.x = fmaf(w5.y, v5.x, acc1.x); acc1.y = fmaf(w5.y, v5.y, acc1.y);
        acc1.z = fmaf(w5.y, v5.z, acc1.z); acc1.w = fmaf(w5.y, v5.w, acc1.w);
        acc0.x = fmaf(w6.x, v6.x, acc0.x); acc0.y = fmaf(w6.x, v6.y, acc0.y);
        acc0.z = fmaf(w6.x, v6.z, acc0.z); acc0.w = fmaf(w6.x, v6.w, acc0.w);
        acc1.x = fmaf(w6.y, v6.x, acc1.x); acc1.y = fmaf(w6.y, v6.y, acc1.y);
        acc1.z = fmaf(w6.y, v6.z, acc1.z); acc1.w = fmaf(w6.y, v6.w, acc1.w);
        acc0.x = fmaf(w7.x, v7.x, acc0.x); acc0.y = fmaf(w7.x, v7.y, acc0.y);
        acc0.z = fmaf(w7.x, v7.z, acc0.z); acc0.w = fmaf(w7.x, v7.w, acc0.w);
        acc1.x = fmaf(w7.y, v7.x, acc1.x); acc1.y = fmaf(w7.y, v7.y, acc1.y);
        acc1.z = fmaf(w7.y, v7.z, acc1.z); acc1.w = fmaf(w7.y, v7.w, acc1.w);
    }

    if (tid >= 256) {
        comb[slot] = acc0;
        comb[256 + slot] = acc1;
    }
    __syncthreads();
    if (tid < 256) {
        float4 u0 = comb[slot];
        float4 u1 = comb[256 + slot];
        acc0.x += u0.x; acc0.y += u0.y; acc0.z += u0.z; acc0.w += u0.w;
        acc1.x += u1.x; acc1.y += u1.y; acc1.z += u1.z; acc1.w += u1.w;
        size_t o = ((size_t)(nc * 64 + b)) * HDIM + slot * 4;
        *(float4*)(p0 + o) = acc0;
        *(float4*)(p1 + o) = acc1;
    }
}

// ---------------- K2: denom per b -> w_out = e/sum, inv[b] ------------------
__global__ __launch_bounds__(512) void k_denom(const float* __restrict__ e,
                                               float* __restrict__ w_out,
                                               float* __restrict__ invArr) {
    __shared__ float red[8];
    int b = blockIdx.x;
    int tid = threadIdx.x;
    int wave = tid >> 6, lane = tid & 63;

    float ev = e[b * 512 + tid];
    float t = ev;
#pragma unroll
    for (int off = 32; off; off >>= 1) t += __shfl_xor(t, off);
    if (lane == 0) red[wave] = t;
    __syncthreads();
    float tot = red[0];
#pragma unroll
    for (int i = 1; i < 8; ++i) tot += red[i];
    float inv = 1.f / tot;
    w_out[b * 512 + tid] = ev * inv;
    if (tid == 0) invArr[b] = inv;
}

// ---------------- K3: u = inv[b] * sum_nc p ---------------------------------
__global__ __launch_bounds__(256) void k_redu(const float* __restrict__ p0,
                                              const float* __restrict__ p1,
                                              const float* __restrict__ invArr,
                                              float* __restrict__ u0,
                                              float* __restrict__ u1) {
    int b = blockIdx.x >> 1;
    int arr = blockIdx.x & 1;
    int tid = threadIdx.x;
    const float* p = arr ? p1 : p0;
    float* u = arr ? u1 : u0;
    float inv = invArr[b];
    float4 a = {0.f, 0.f, 0.f, 0.f};
#pragma unroll
    for (int nc = 0; nc < 16; ++nc) {
        float4 v = *(const float4*)(p + ((size_t)(nc * 64 + b)) * HDIM + tid * 4);
        a.x += v.x; a.y += v.y; a.z += v.z; a.w += v.w;
    }
    a.x *= inv; a.y *= inv; a.z *= inv; a.w *= inv;
    *(float4*)(u + (size_t)b * HDIM + tid * 4) = a;
}

// ---------------- K4: split-k GEMM partials: pOut[kc][h][b] -----------------
__global__ __launch_bounds__(256) void k_out(const float* __restrict__ u0,
                                             const float* __restrict__ u1,
                                             const float* __restrict__ Wr0,
                                             const float* __restrict__ Wr1,
                                             float* __restrict__ pOut) {
    __shared__ float lds[64 * 128];
    int tid = threadIdx.x;
    int ht = blockIdx.x >> 4;
    int kc = blockIdx.x & 15;
    const float* usrc = (kc < 8) ? u0 : u1;
    const float* wsrc = (kc < 8) ? Wr0 : Wr1;
    int koff = (kc & 7) * 128;
    int h0 = ht * 64;

    {
        int c4 = tid & 31;
        int r2 = tid >> 5;
#pragma unroll
        for (int i = 0; i < 8; ++i) {
            int row = i * 8 + r2;
            float4 v = *(const float4*)(usrc + (size_t)row * HDIM + koff + c4 * 4);
            *(float4*)&lds[row * 128 + ((c4 ^ (row & 7)) << 2)] = v;
        }
    }
    __syncthreads();

    int b = tid & 63;
    int wu = __builtin_amdgcn_readfirstlane(tid >> 6);
    int hbase = h0 + wu * 16;
    const float* wrow = wsrc + (size_t)hbase * HDIM + koff;

    float acc[16];
#pragma unroll
    for (int j = 0; j < 16; ++j) acc[j] = 0.f;

#pragma unroll 4
    for (int k4 = 0; k4 < 32; ++k4) {
        float4 uv = *(float4*)&lds[b * 128 + ((k4 ^ (b & 7)) << 2)];
#pragma unroll
        for (int j = 0; j < 16; ++j) {
            float4 wv = *(const float4*)(wrow + (size_t)j * HDIM + k4 * 4);
            acc[j] = fmaf(uv.x, wv.x, acc[j]);
            acc[j] = fmaf(uv.y, wv.y, acc[j]);
            acc[j] = fmaf(uv.z, wv.z, acc[j]);
            acc[j] = fmaf(uv.w, wv.w, acc[j]);
        }
    }
#pragma unroll
    for (int j = 0; j < 16; ++j)
        pOut[((size_t)kc * HDIM + hbase + j) * 64 + b] = acc[j];
}

// ---------------- K5: reduce 16 k-chunks -> attn_sum[b][h] ------------------
__global__ __launch_bounds__(256) void k_redout(const float* __restrict__ pOut,
                                                float* __restrict__ out1) {
    int tid = threadIdx.x;
    int b = tid & 63;
    int h = blockIdx.x * 4 + (tid >> 6);
    float acc = 0.f;
#pragma unroll
    for (int kc = 0; kc < 16; ++kc)
        acc += pOut[((size_t)kc * HDIM + h) * 64 + b];
    out1[(size_t)b * HDIM + h] = acc;
}

extern "C" void kernel_launch(void* const* d_in, const int* in_sizes, int n_in,
                              void* d_out, int out_size, void* d_ws, size_t ws_size,
                              hipStream_t stream) {
    const float* Kmat  = (const float*)d_in[1];
    const float* V     = (const float*)d_in[2];
    const int*   adj   = (const int*)d_in[3];
    const int*   smask = (const int*)d_in[4];
    const int*   omask = (const int*)d_in[5];
    const float* Watt  = (const float*)d_in[6];
    const float* Wr0   = (const float*)d_in[8];
    const float* Wr1   = (const float*)d_in[9];
    float* out = (float*)d_out;
    float* ws  = (float*)d_ws;

    float* e    = ws;                 //  64*512   = 32768
    float* inv  = ws + 32768;         //  64 (pad 128)
    float* p0   = ws + 32896;         //  16*64*1024 = 1048576
    float* p1   = ws + 1081472;       //  16*64*1024 = 1048576
    float* u0   = ws + 2130048;       //  64*1024 = 65536
    float* u1   = ws + 2195584;       //  64*1024 = 65536
    float* pOut = ws + 2261120;       //  16*1024*64 = 1048576
    const float* Wk = Watt + HDIM;

    k_fused  <<<1024, 512, 0, stream>>>(Kmat, V, adj, smask, omask, Wk, e, p0, p1);
    k_denom  <<<  64, 512, 0, stream>>>(e, out, inv);
    k_redu   <<< 128, 256, 0, stream>>>(p0, p1, inv, u0, u1);
    k_out    <<< 256, 256, 0, stream>>>(u0, u1, Wr0, Wr1, pOut);
    k_redout <<< 256, 256, 0, stream>>>(pOut, out + 32768);
}

// Round 5
// 93.811 us; speedup vs baseline: 1.0317x; 1.0129x over previous
//
#include <hip/hip_runtime.h>
#include <math.h>

#define HDIM 1024
#define BDIM 64
#define NDIM 512

// ---------------- K1: fused score+exp+mask+V-weighting (forced-MLP) ---------
// grid 1024 blocks (b*16+nc), 512 threads = 8 waves. Chunk = 32 n-rows.
// Phase 1: wave w computes rows 4w..4w+3; all 16 float4 K-loads issued before
//          any FMA (sched_barrier fence) -> 16 KB/wave in flight.
// Phase 2: 512 threads = 2 row-halves x 256 h-slots; all 16 V-loads issued
//          before FMAs; halves combined through LDS.
__global__ __launch_bounds__(512) void k_fused(const float* __restrict__ Kmat,
                                               const float* __restrict__ V,
                                               const int* __restrict__ adj,
                                               const int* __restrict__ smask,
                                               const int* __restrict__ omask,
                                               const float* __restrict__ Wk,
                                               float* __restrict__ e_out,
                                               float* __restrict__ p0,
                                               float* __restrict__ p1) {
    __shared__ float2 eso[32];
    __shared__ int mA[32], mS[32], mO[32];
    __shared__ float4 comb[512];    // 8 KB combine buffer
    int b = blockIdx.x >> 4;
    int nc = blockIdx.x & 15;
    int tid = threadIdx.x;
    int wave = tid >> 6, lane = tid & 63;
    int gbase = b * 512 + nc * 32;

    if (tid < 32) {
        mA[tid] = adj[gbase + tid];
        mS[tid] = smask[gbase + tid];
        mO[tid] = omask[gbase + tid];
    }
    const float4* wk4 = (const float4*)Wk;
    float4 wk0 = wk4[lane], wk1 = wk4[64 + lane],
           wk2 = wk4[128 + lane], wk3 = wk4[192 + lane];
    __syncthreads();

    // ---- phase 1: 4 rows per wave; 16 loads in flight before any FMA ------
    {
        int r0 = wave * 4;
        const float4* kp = (const float4*)(Kmat + (size_t)(gbase + r0) * HDIM);
        float4 kv[16];
#pragma unroll
        for (int r = 0; r < 4; ++r) {
#pragma unroll
            for (int i = 0; i < 4; ++i)
                kv[r * 4 + i] = kp[r * 256 + i * 64 + lane];
        }
        __builtin_amdgcn_sched_barrier(0);

        float s[4];
#pragma unroll
        for (int r = 0; r < 4; ++r) {
            float t = 0.f;
            t = fmaf(kv[r*4+0].x, wk0.x, t); t = fmaf(kv[r*4+0].y, wk0.y, t);
            t = fmaf(kv[r*4+0].z, wk0.z, t); t = fmaf(kv[r*4+0].w, wk0.w, t);
            t = fmaf(kv[r*4+1].x, wk1.x, t); t = fmaf(kv[r*4+1].y, wk1.y, t);
            t = fmaf(kv[r*4+1].z, wk1.z, t); t = fmaf(kv[r*4+1].w, wk1.w, t);
            t = fmaf(kv[r*4+2].x, wk2.x, t); t = fmaf(kv[r*4+2].y, wk2.y, t);
            t = fmaf(kv[r*4+2].z, wk2.z, t); t = fmaf(kv[r*4+2].w, wk2.w, t);
            t = fmaf(kv[r*4+3].x, wk3.x, t); t = fmaf(kv[r*4+3].y, wk3.y, t);
            t = fmaf(kv[r*4+3].z, wk3.z, t); t = fmaf(kv[r*4+3].w, wk3.w, t);
            s[r] = t;
        }
#pragma unroll
        for (int off = 32; off; off >>= 1) {
#pragma unroll
            for (int r = 0; r < 4; ++r) s[r] += __shfl_xor(s[r], off);
        }
        if (lane == 0) {
#pragma unroll
            for (int r = 0; r < 4; ++r) {
                int row = r0 + r;
                float e = mA[row] ? expf(s[r]) : 0.f;
                e_out[gbase + row] = e;
                eso[row] = make_float2(mS[row] ? e : 0.f, mO[row] ? e : 0.f);
            }
        }
    }
    __syncthreads();

    // ---- phase 2: 16 rows per thread-half; 16 loads in flight -------------
    int slot = tid & 255;
    int rbase = (tid >> 8) * 16;   // 0 or 16
    const float4* vp = (const float4*)(V + (size_t)(gbase + rbase) * HDIM) + slot;
    float4 v[16];
#pragma unroll
    for (int i = 0; i < 16; ++i) v[i] = vp[i * 256];
    __builtin_amdgcn_sched_barrier(0);

    float4 acc0 = {0.f, 0.f, 0.f, 0.f};
    float4 acc1 = {0.f, 0.f, 0.f, 0.f};
#pragma unroll
    for (int i = 0; i < 16; ++i) {
        float2 w = eso[rbase + i];
        acc0.x = fmaf(w.x, v[i].x, acc0.x); acc0.y = fmaf(w.x, v[i].y, acc0.y);
        acc0.z = fmaf(w.x, v[i].z, acc0.z); acc0.w = fmaf(w.x, v[i].w, acc0.w);
        acc1.x = fmaf(w.y, v[i].x, acc1.x); acc1.y = fmaf(w.y, v[i].y, acc1.y);
        acc1.z = fmaf(w.y, v[i].z, acc1.z); acc1.w = fmaf(w.y, v[i].w, acc1.w);
    }

    if (tid >= 256) {
        comb[slot] = acc0;
        comb[256 + slot] = acc1;
    }
    __syncthreads();
    if (tid < 256) {
        float4 u0 = comb[slot];
        float4 u1 = comb[256 + slot];
        acc0.x += u0.x; acc0.y += u0.y; acc0.z += u0.z; acc0.w += u0.w;
        acc1.x += u1.x; acc1.y += u1.y; acc1.z += u1.z; acc1.w += u1.w;
        size_t o = ((size_t)(nc * 64 + b)) * HDIM + slot * 4;
        *(float4*)(p0 + o) = acc0;
        *(float4*)(p1 + o) = acc1;
    }
}

// ---------------- K2: denom per b -> w_out = e/sum, inv[b] ------------------
__global__ __launch_bounds__(512) void k_denom(const float* __restrict__ e,
                                               float* __restrict__ w_out,
                                               float* __restrict__ invArr) {
    __shared__ float red[8];
    int b = blockIdx.x;
    int tid = threadIdx.x;
    int wave = tid >> 6, lane = tid & 63;

    float ev = e[b * 512 + tid];
    float t = ev;
#pragma unroll
    for (int off = 32; off; off >>= 1) t += __shfl_xor(t, off);
    if (lane == 0) red[wave] = t;
    __syncthreads();
    float tot = red[0];
#pragma unroll
    for (int i = 1; i < 8; ++i) tot += red[i];
    float inv = 1.f / tot;
    w_out[b * 512 + tid] = ev * inv;
    if (tid == 0) invArr[b] = inv;
}

// ---------------- K3: u = inv[b] * sum_nc p ---------------------------------
__global__ __launch_bounds__(256) void k_redu(const float* __restrict__ p0,
                                              const float* __restrict__ p1,
                                              const float* __restrict__ invArr,
                                              float* __restrict__ u0,
                                              float* __restrict__ u1) {
    int b = blockIdx.x >> 1;
    int arr = blockIdx.x & 1;
    int tid = threadIdx.x;
    const float* p = arr ? p1 : p0;
    float* u = arr ? u1 : u0;
    float inv = invArr[b];
    float4 a = {0.f, 0.f, 0.f, 0.f};
#pragma unroll
    for (int nc = 0; nc < 16; ++nc) {
        float4 v = *(const float4*)(p + ((size_t)(nc * 64 + b)) * HDIM + tid * 4);
        a.x += v.x; a.y += v.y; a.z += v.z; a.w += v.w;
    }
    a.x *= inv; a.y *= inv; a.z *= inv; a.w *= inv;
    *(float4*)(u + (size_t)b * HDIM + tid * 4) = a;
}

// ---------------- K4: split-k GEMM partials: pOut[kc][h][b] -----------------
__global__ __launch_bounds__(256) void k_out(const float* __restrict__ u0,
                                             const float* __restrict__ u1,
                                             const float* __restrict__ Wr0,
                                             const float* __restrict__ Wr1,
                                             float* __restrict__ pOut) {
    __shared__ float lds[64 * 128];
    int tid = threadIdx.x;
    int ht = blockIdx.x >> 4;
    int kc = blockIdx.x & 15;
    const float* usrc = (kc < 8) ? u0 : u1;
    const float* wsrc = (kc < 8) ? Wr0 : Wr1;
    int koff = (kc & 7) * 128;
    int h0 = ht * 64;

    {
        int c4 = tid & 31;
        int r2 = tid >> 5;
#pragma unroll
        for (int i = 0; i < 8; ++i) {
            int row = i * 8 + r2;
            float4 v = *(const float4*)(usrc + (size_t)row * HDIM + koff + c4 * 4);
            *(float4*)&lds[row * 128 + ((c4 ^ (row & 7)) << 2)] = v;
        }
    }
    __syncthreads();

    int b = tid & 63;
    int wu = __builtin_amdgcn_readfirstlane(tid >> 6);
    int hbase = h0 + wu * 16;
    const float* wrow = wsrc + (size_t)hbase * HDIM + koff;

    float acc[16];
#pragma unroll
    for (int j = 0; j < 16; ++j) acc[j] = 0.f;

#pragma unroll 4
    for (int k4 = 0; k4 < 32; ++k4) {
        float4 uv = *(float4*)&lds[b * 128 + ((k4 ^ (b & 7)) << 2)];
#pragma unroll
        for (int j = 0; j < 16; ++j) {
            float4 wv = *(const float4*)(wrow + (size_t)j * HDIM + k4 * 4);
            acc[j] = fmaf(uv.x, wv.x, acc[j]);
            acc[j] = fmaf(uv.y, wv.y, acc[j]);
            acc[j] = fmaf(uv.z, wv.z, acc[j]);
            acc[j] = fmaf(uv.w, wv.w, acc[j]);
        }
    }
#pragma unroll
    for (int j = 0; j < 16; ++j)
        pOut[((size_t)kc * HDIM + hbase + j) * 64 + b] = acc[j];
}

// ---------------- K5: reduce 16 k-chunks -> attn_sum[b][h] ------------------
__global__ __launch_bounds__(256) void k_redout(const float* __restrict__ pOut,
                                                float* __restrict__ out1) {
    int tid = threadIdx.x;
    int b = tid & 63;
    int h = blockIdx.x * 4 + (tid >> 6);
    float acc = 0.f;
#pragma unroll
    for (int kc = 0; kc < 16; ++kc)
        acc += pOut[((size_t)kc * HDIM + h) * 64 + b];
    out1[(size_t)b * HDIM + h] = acc;
}

extern "C" void kernel_launch(void* const* d_in, const int* in_sizes, int n_in,
                              void* d_out, int out_size, void* d_ws, size_t ws_size,
                              hipStream_t stream) {
    const float* Kmat  = (const float*)d_in[1];
    const float* V     = (const float*)d_in[2];
    const int*   adj   = (const int*)d_in[3];
    const int*   smask = (const int*)d_in[4];
    const int*   omask = (const int*)d_in[5];
    const float* Watt  = (const float*)d_in[6];
    const float* Wr0   = (const float*)d_in[8];
    const float* Wr1   = (const float*)d_in[9];
    float* out = (float*)d_out;
    float* ws  = (float*)d_ws;

    float* e    = ws;                 //  64*512   = 32768
    float* inv  = ws + 32768;         //  64 (pad 128)
    float* p0   = ws + 32896;         //  16*64*1024 = 1048576
    float* p1   = ws + 1081472;       //  16*64*1024 = 1048576
    float* u0   = ws + 2130048;       //  64*1024 = 65536
    float* u1   = ws + 2195584;       //  64*1024 = 65536
    float* pOut = ws + 2261120;       //  16*1024*64 = 1048576
    const float* Wk = Watt + HDIM;

    k_fused  <<<1024, 512, 0, stream>>>(Kmat, V, adj, smask, omask, Wk, e, p0, p1);
    k_denom  <<<  64, 512, 0, stream>>>(e, out, inv);
    k_redu   <<< 128, 256, 0, stream>>>(p0, p1, inv, u0, u1);
    k_out    <<< 256, 256, 0, stream>>>(u0, u1, Wr0, Wr1, pOut);
    k_redout <<< 256, 256, 0, stream>>>(pOut, out + 32768);
}

// Round 6
// 74.989 us; speedup vs baseline: 1.2906x; 1.2510x over previous
//
#include <hip/hip_runtime.h>
#include <math.h>

#define HDIM 1024
#define BDIM 64
#define NDIM 512
#define INVB (1 << 15)

// ---------------- K0: compact row lists from masks --------------------------
// grid 64 blocks (per b) x 512 threads.
// idxK: rows with adj=1 (these need a K-row score).  pad to x2, sentinel INVB.
// idxV: rows with adj=1 && (s|o), code n | s<<14 | o<<15.  pad to x8, code 0.
__global__ __launch_bounds__(512) void k_prep(const int* __restrict__ adj,
                                              const int* __restrict__ sm,
                                              const int* __restrict__ om,
                                              int* __restrict__ idxK,
                                              int* __restrict__ cntKp,
                                              int* __restrict__ idxV,
                                              int* __restrict__ cntVp) {
    __shared__ int cK[8], cV[8];
    int b = blockIdx.x;
    int n = threadIdx.x;
    int wave = n >> 6, lane = n & 63;
    int idx = b * 512 + n;
    int a = adj[idx], s = sm[idx], o = om[idx];
    int predK = (a != 0);
    int predV = (a != 0) && ((s | o) != 0);
    unsigned long long mK = __ballot(predK);
    unsigned long long mV = __ballot(predV);
    if (lane == 0) { cK[wave] = __popcll(mK); cV[wave] = __popcll(mV); }
    __syncthreads();
    int offK = 0, offV = 0;
    for (int i = 0; i < wave; ++i) { offK += cK[i]; offV += cV[i]; }
    unsigned long long lt = (1ull << lane) - 1ull;
    int pK = offK + __popcll(mK & lt);
    int pV = offV + __popcll(mV & lt);
    if (predK) idxK[b * 512 + pK] = n;
    if (predV) idxV[b * 512 + pV] = n | (s << 14) | (o << 15);
    if (n == 0) {
        int cntK = 0, cntV = 0;
        for (int i = 0; i < 8; ++i) { cntK += cK[i]; cntV += cV[i]; }
        int kp = (cntK + 1) & ~1;
        int vp = (cntV + 7) & ~7;
        for (int i = cntK; i < kp; ++i) idxK[b * 512 + i] = INVB;  // invalid row
        for (int i = cntV; i < vp; ++i) idxV[b * 512 + i] = 0;     // zero-weight
        cntKp[b] = kp;
        cntVp[b] = vp;
    }
}

// ---------------- K1: e[b][n] = exp(dot(K[row], Wk)) for compacted rows -----
// grid 2048 blocks (b*32+chunk) x 512 threads; wave does 2 rows, 8 loads deep.
__global__ __launch_bounds__(512) void k_scores(const float* __restrict__ Kmat,
                                                const float* __restrict__ Wk,
                                                const int* __restrict__ idxK,
                                                const int* __restrict__ cntKp,
                                                float* __restrict__ e_out) {
    int b = blockIdx.x >> 5;
    int chunk = blockIdx.x & 31;
    int tid = threadIdx.x;
    int wave = tid >> 6, lane = tid & 63;
    int slot = chunk * 16 + wave * 2;
    if (slot >= cntKp[b]) return;

    const float4* wk4 = (const float4*)Wk;
    float4 wk0 = wk4[lane], wk1 = wk4[64 + lane],
           wk2 = wk4[128 + lane], wk3 = wk4[192 + lane];
    int c0 = idxK[b * 512 + slot];
    int c1 = idxK[b * 512 + slot + 1];
    int n0 = c0 & 1023, n1 = c1 & 1023;
    const float4* kp0 = (const float4*)(Kmat + (size_t)(b * 512 + n0) * HDIM);
    const float4* kp1 = (const float4*)(Kmat + (size_t)(b * 512 + n1) * HDIM);

    float4 a0 = kp0[lane],       a1 = kp0[64 + lane],
           a2 = kp0[128 + lane], a3 = kp0[192 + lane];
    float4 c0v = kp1[lane],       c1v = kp1[64 + lane],
           c2v = kp1[128 + lane], c3v = kp1[192 + lane];
    __builtin_amdgcn_sched_barrier(0);

    float s0 = 0.f, s1 = 0.f;
    s0 = fmaf(a0.x, wk0.x, s0); s0 = fmaf(a0.y, wk0.y, s0);
    s0 = fmaf(a0.z, wk0.z, s0); s0 = fmaf(a0.w, wk0.w, s0);
    s0 = fmaf(a1.x, wk1.x, s0); s0 = fmaf(a1.y, wk1.y, s0);
    s0 = fmaf(a1.z, wk1.z, s0); s0 = fmaf(a1.w, wk1.w, s0);
    s0 = fmaf(a2.x, wk2.x, s0); s0 = fmaf(a2.y, wk2.y, s0);
    s0 = fmaf(a2.z, wk2.z, s0); s0 = fmaf(a2.w, wk2.w, s0);
    s0 = fmaf(a3.x, wk3.x, s0); s0 = fmaf(a3.y, wk3.y, s0);
    s0 = fmaf(a3.z, wk3.z, s0); s0 = fmaf(a3.w, wk3.w, s0);
    s1 = fmaf(c0v.x, wk0.x, s1); s1 = fmaf(c0v.y, wk0.y, s1);
    s1 = fmaf(c0v.z, wk0.z, s1); s1 = fmaf(c0v.w, wk0.w, s1);
    s1 = fmaf(c1v.x, wk1.x, s1); s1 = fmaf(c1v.y, wk1.y, s1);
    s1 = fmaf(c1v.z, wk1.z, s1); s1 = fmaf(c1v.w, wk1.w, s1);
    s1 = fmaf(c2v.x, wk2.x, s1); s1 = fmaf(c2v.y, wk2.y, s1);
    s1 = fmaf(c2v.z, wk2.z, s1); s1 = fmaf(c2v.w, wk2.w, s1);
    s1 = fmaf(c3v.x, wk3.x, s1); s1 = fmaf(c3v.y, wk3.y, s1);
    s1 = fmaf(c3v.z, wk3.z, s1); s1 = fmaf(c3v.w, wk3.w, s1);

#pragma unroll
    for (int off = 32; off; off >>= 1) {
        s0 += __shfl_xor(s0, off);
        s1 += __shfl_xor(s1, off);
    }
    if (lane == 0) {
        if (!(c0 & INVB)) e_out[b * 512 + n0] = expf(s0);
        if (!(c1 & INVB)) e_out[b * 512 + n1] = expf(s1);
    }
}

// ---------------- K2: denom per b -> w_out = adj? e/sum : 0, inv[b] ---------
__global__ __launch_bounds__(512) void k_denom(const float* __restrict__ e,
                                               const int* __restrict__ adj,
                                               float* __restrict__ w_out,
                                               float* __restrict__ invArr) {
    __shared__ float red[8];
    int b = blockIdx.x;
    int tid = threadIdx.x;
    int wave = tid >> 6, lane = tid & 63;
    int idx = b * 512 + tid;

    float ev = adj[idx] ? e[idx] : 0.f;
    float t = ev;
#pragma unroll
    for (int off = 32; off; off >>= 1) t += __shfl_xor(t, off);
    if (lane == 0) red[wave] = t;
    __syncthreads();
    float tot = red[0];
#pragma unroll
    for (int i = 1; i < 8; ++i) tot += red[i];
    float inv = 1.f / tot;
    w_out[idx] = ev * inv;
    if (tid == 0) invArr[b] = inv;
}

// ---------------- K3: p0/p1[chunk][b][h] over compacted V rows --------------
// grid 2048 blocks (b*32+chunk) x 256 threads; chunk = 16 compacted rows.
__global__ __launch_bounds__(256) void k_weightv(const float* __restrict__ V,
                                                 const float* __restrict__ e,
                                                 const int* __restrict__ idxV,
                                                 const int* __restrict__ cntVp,
                                                 float* __restrict__ p0,
                                                 float* __restrict__ p1) {
    __shared__ float2 wbuf[16];
    __shared__ int nbuf[16];
    int b = blockIdx.x >> 5;
    int chunk = blockIdx.x & 31;
    int tid = threadIdx.x;
    int start = chunk * 16;
    int avail = cntVp[b] - start;
    int rows = avail < 0 ? 0 : (avail > 16 ? 16 : avail);   // 0, 8, or 16

    if (tid < rows) {
        int code = idxV[b * 512 + start + tid];
        int n = code & 1023;
        float ev = e[b * 512 + n];
        float2 w;
        w.x = (code & (1 << 14)) ? ev : 0.f;
        w.y = (code & (1 << 15)) ? ev : 0.f;
        wbuf[tid] = w;
        nbuf[tid] = n;
    }
    __syncthreads();

    const float* Vb = V + (size_t)(b * 512) * HDIM;
    float4 a0 = {0.f, 0.f, 0.f, 0.f};
    float4 a1 = {0.f, 0.f, 0.f, 0.f};
    for (int g = 0; g < (rows >> 3); ++g) {
        int nn[8];
#pragma unroll
        for (int i = 0; i < 8; ++i) nn[i] = nbuf[g * 8 + i];
        float4 v[8];
#pragma unroll
        for (int i = 0; i < 8; ++i)
            v[i] = *((const float4*)(Vb + (size_t)nn[i] * HDIM) + tid);
        __builtin_amdgcn_sched_barrier(0);
#pragma unroll
        for (int i = 0; i < 8; ++i) {
            float2 w = wbuf[g * 8 + i];
            a0.x = fmaf(w.x, v[i].x, a0.x); a0.y = fmaf(w.x, v[i].y, a0.y);
            a0.z = fmaf(w.x, v[i].z, a0.z); a0.w = fmaf(w.x, v[i].w, a0.w);
            a1.x = fmaf(w.y, v[i].x, a1.x); a1.y = fmaf(w.y, v[i].y, a1.y);
            a1.z = fmaf(w.y, v[i].z, a1.z); a1.w = fmaf(w.y, v[i].w, a1.w);
        }
    }
    size_t off = ((size_t)(chunk * 64 + b)) * HDIM + tid * 4;
    *(float4*)(p0 + off) = a0;
    *(float4*)(p1 + off) = a1;
}

// ---------------- K4: u = inv[b] * sum_32chunks p ---------------------------
__global__ __launch_bounds__(256) void k_redu(const float* __restrict__ p0,
                                              const float* __restrict__ p1,
                                              const float* __restrict__ invArr,
                                              float* __restrict__ u0,
                                              float* __restrict__ u1) {
    int b = blockIdx.x >> 1;
    int arr = blockIdx.x & 1;
    int tid = threadIdx.x;
    const float* p = arr ? p1 : p0;
    float* u = arr ? u1 : u0;
    float inv = invArr[b];
    float4 a = {0.f, 0.f, 0.f, 0.f};
#pragma unroll
    for (int nc = 0; nc < 32; ++nc) {
        float4 v = *(const float4*)(p + ((size_t)(nc * 64 + b)) * HDIM + tid * 4);
        a.x += v.x; a.y += v.y; a.z += v.z; a.w += v.w;
    }
    a.x *= inv; a.y *= inv; a.z *= inv; a.w *= inv;
    *(float4*)(u + (size_t)b * HDIM + tid * 4) = a;
}

// ---------------- K5: split-k GEMM partials: pOut[kc][h][b] -----------------
__global__ __launch_bounds__(256) void k_out(const float* __restrict__ u0,
                                             const float* __restrict__ u1,
                                             const float* __restrict__ Wr0,
                                             const float* __restrict__ Wr1,
                                             float* __restrict__ pOut) {
    __shared__ float lds[64 * 128];
    int tid = threadIdx.x;
    int ht = blockIdx.x >> 4;
    int kc = blockIdx.x & 15;
    const float* usrc = (kc < 8) ? u0 : u1;
    const float* wsrc = (kc < 8) ? Wr0 : Wr1;
    int koff = (kc & 7) * 128;
    int h0 = ht * 64;

    {
        int c4 = tid & 31;
        int r2 = tid >> 5;
#pragma unroll
        for (int i = 0; i < 8; ++i) {
            int row = i * 8 + r2;
            float4 v = *(const float4*)(usrc + (size_t)row * HDIM + koff + c4 * 4);
            *(float4*)&lds[row * 128 + ((c4 ^ (row & 7)) << 2)] = v;
        }
    }
    __syncthreads();

    int b = tid & 63;
    int wu = __builtin_amdgcn_readfirstlane(tid >> 6);
    int hbase = h0 + wu * 16;
    const float* wrow = wsrc + (size_t)hbase * HDIM + koff;

    float acc[16];
#pragma unroll
    for (int j = 0; j < 16; ++j) acc[j] = 0.f;

#pragma unroll 4
    for (int k4 = 0; k4 < 32; ++k4) {
        float4 uv = *(float4*)&lds[b * 128 + ((k4 ^ (b & 7)) << 2)];
#pragma unroll
        for (int j = 0; j < 16; ++j) {
            float4 wv = *(const float4*)(wrow + (size_t)j * HDIM + k4 * 4);
            acc[j] = fmaf(uv.x, wv.x, acc[j]);
            acc[j] = fmaf(uv.y, wv.y, acc[j]);
            acc[j] = fmaf(uv.z, wv.z, acc[j]);
            acc[j] = fmaf(uv.w, wv.w, acc[j]);
        }
    }
#pragma unroll
    for (int j = 0; j < 16; ++j)
        pOut[((size_t)kc * HDIM + hbase + j) * 64 + b] = acc[j];
}

// ---------------- K6: reduce 16 k-chunks -> attn_sum[b][h] ------------------
__global__ __launch_bounds__(256) void k_redout(const float* __restrict__ pOut,
                                                float* __restrict__ out1) {
    int tid = threadIdx.x;
    int b = tid & 63;
    int h = blockIdx.x * 4 + (tid >> 6);
    float acc = 0.f;
#pragma unroll
    for (int kc = 0; kc < 16; ++kc)
        acc += pOut[((size_t)kc * HDIM + h) * 64 + b];
    out1[(size_t)b * HDIM + h] = acc;
}

extern "C" void kernel_launch(void* const* d_in, const int* in_sizes, int n_in,
                              void* d_out, int out_size, void* d_ws, size_t ws_size,
                              hipStream_t stream) {
    const float* Kmat  = (const float*)d_in[1];
    const float* V     = (const float*)d_in[2];
    const int*   adj   = (const int*)d_in[3];
    const int*   smask = (const int*)d_in[4];
    const int*   omask = (const int*)d_in[5];
    const float* Watt  = (const float*)d_in[6];
    const float* Wr0   = (const float*)d_in[8];
    const float* Wr1   = (const float*)d_in[9];
    float* out = (float*)d_out;
    float* ws  = (float*)d_ws;

    // ws layout (float offsets)
    float* e    = ws;                    //  64*512            = 32768
    float* inv  = ws + 32768;            //  64  (pad 128)
    int*   idxK = (int*)(ws + 32896);    //  64*512            = 32768
    int*   cKp  = (int*)(ws + 65664);    //  64  (pad 128)
    int*   idxV = (int*)(ws + 65792);    //  64*512            = 32768
    int*   cVp  = (int*)(ws + 98560);    //  64  (pad 128)
    float* p0   = ws + 98688;            //  32*64*1024        = 2097152
    float* p1   = ws + 2195840;          //  32*64*1024        = 2097152
    float* u0   = ws + 4292992;          //  64*1024           = 65536
    float* u1   = ws + 4358528;          //  64*1024           = 65536
    float* pOut = ws + 4424064;          //  16*1024*64        = 1048576
    const float* Wk = Watt + HDIM;       // second half of W_att

    k_prep   <<<  64, 512, 0, stream>>>(adj, smask, omask, idxK, cKp, idxV, cVp);
    k_scores <<<2048, 512, 0, stream>>>(Kmat, Wk, idxK, cKp, e);
    k_denom  <<<  64, 512, 0, stream>>>(e, adj, out, inv);
    k_weightv<<<2048, 256, 0, stream>>>(V, e, idxV, cVp, p0, p1);
    k_redu   <<< 128, 256, 0, stream>>>(p0, p1, inv, u0, u1);
    k_out    <<< 256, 256, 0, stream>>>(u0, u1, Wr0, Wr1, pOut);
    k_redout <<< 256, 256, 0, stream>>>(pOut, out + 32768);
}

// Round 7
// 69.194 us; speedup vs baseline: 1.3987x; 1.0838x over previous
//
#include <hip/hip_runtime.h>
#include <math.h>

#define HDIM 1024
#define BDIM 64
#define NDIM 512
#define INVB (1 << 13)
#define SBIT (1 << 14)
#define OBIT (1 << 15)
#define SLOTS 20

// ---------------- K0: compacted adj-row list with mask bits -----------------
// grid 64 blocks (per b) x 512 threads.
// idxK: rows with adj=1, code = n | s<<14 | o<<15; padded to x16 with INVB.
__global__ __launch_bounds__(512) void k_prep(const int* __restrict__ adj,
                                              const int* __restrict__ sm,
                                              const int* __restrict__ om,
                                              int* __restrict__ idxK,
                                              int* __restrict__ cntKp) {
    __shared__ int cK[8];
    int b = blockIdx.x;
    int n = threadIdx.x;
    int wave = n >> 6, lane = n & 63;
    int idx = b * 512 + n;
    int a = adj[idx], s = sm[idx], o = om[idx];
    int predK = (a != 0);
    unsigned long long mK = __ballot(predK);
    if (lane == 0) cK[wave] = __popcll(mK);
    __syncthreads();
    int off = 0;
    for (int i = 0; i < wave; ++i) off += cK[i];
    unsigned long long lt = (1ull << lane) - 1ull;
    int pK = off + __popcll(mK & lt);
    if (predK) idxK[b * 512 + pK] = n | (s << 14) | (o << 15);
    if (n == 0) {
        int cnt = 0;
        for (int i = 0; i < 8; ++i) cnt += cK[i];
        int kp = (cnt + 15) & ~15;
        for (int i = cnt; i < kp; ++i) idxK[b * 512 + i] = INVB;
        cntKp[b] = kp;
    }
}

// ---------------- K1: fused score+exp -> e, and V-weight partials -----------
// grid 64*SLOTS blocks x 256 threads; chunk = 16 compacted adj rows.
// Phase 1: 4 waves x 4 rows -> e = exp(dot(K,Wk)), write e_out, stage weights.
// Compaction: wave 0 builds the (s|o)-active sublist in LDS.
// Phase 2: stream only active V rows, 8-deep load batches.
__global__ __launch_bounds__(256) void k_fusedA(const float* __restrict__ Kmat,
                                                const float* __restrict__ V,
                                                const float* __restrict__ Wk,
                                                const int* __restrict__ idxK,
                                                const int* __restrict__ cntKp,
                                                float* __restrict__ e_out,
                                                float* __restrict__ p0,
                                                float* __restrict__ p1) {
    __shared__ float2 eso[16];
    __shared__ int codeL[16];
    __shared__ float2 cw[24];
    __shared__ int cn[24];
    __shared__ int s_cnz8;
    int b = blockIdx.x / SLOTS;
    int chunk = blockIdx.x - b * SLOTS;
    int tid = threadIdx.x, wave = tid >> 6, lane = tid & 63;
    int start = chunk * 16;
    size_t pbase = ((size_t)(chunk * 64 + b)) * HDIM + tid * 4;

    if (start >= cntKp[b]) {               // inactive slot: zero the partial
        float4 z = {0.f, 0.f, 0.f, 0.f};
        *(float4*)(p0 + pbase) = z;
        *(float4*)(p1 + pbase) = z;
        return;
    }

    if (tid < 16) codeL[tid] = idxK[b * 512 + start + tid];
    const float4* wk4 = (const float4*)Wk;
    float4 wk0 = wk4[lane], wk1 = wk4[64 + lane],
           wk2 = wk4[128 + lane], wk3 = wk4[192 + lane];
    __syncthreads();

    // ---- phase 1: 4 rows per wave, two at a time, 8 loads in flight -------
#pragma unroll
    for (int pp = 0; pp < 2; ++pp) {
        int r0 = wave * 4 + pp * 2;
        int c0 = codeL[r0], c1 = codeL[r0 + 1];
        int n0 = c0 & 511, n1 = c1 & 511;
        const float4* kp0 = (const float4*)(Kmat + (size_t)(b * 512 + n0) * HDIM);
        const float4* kp1 = (const float4*)(Kmat + (size_t)(b * 512 + n1) * HDIM);
        float4 a0 = kp0[lane],       a1 = kp0[64 + lane],
               a2 = kp0[128 + lane], a3 = kp0[192 + lane];
        float4 d0 = kp1[lane],       d1 = kp1[64 + lane],
               d2 = kp1[128 + lane], d3 = kp1[192 + lane];
        __builtin_amdgcn_sched_barrier(0);

        float s0 = 0.f, s1 = 0.f;
        s0 = fmaf(a0.x, wk0.x, s0); s0 = fmaf(a0.y, wk0.y, s0);
        s0 = fmaf(a0.z, wk0.z, s0); s0 = fmaf(a0.w, wk0.w, s0);
        s0 = fmaf(a1.x, wk1.x, s0); s0 = fmaf(a1.y, wk1.y, s0);
        s0 = fmaf(a1.z, wk1.z, s0); s0 = fmaf(a1.w, wk1.w, s0);
        s0 = fmaf(a2.x, wk2.x, s0); s0 = fmaf(a2.y, wk2.y, s0);
        s0 = fmaf(a2.z, wk2.z, s0); s0 = fmaf(a2.w, wk2.w, s0);
        s0 = fmaf(a3.x, wk3.x, s0); s0 = fmaf(a3.y, wk3.y, s0);
        s0 = fmaf(a3.z, wk3.z, s0); s0 = fmaf(a3.w, wk3.w, s0);
        s1 = fmaf(d0.x, wk0.x, s1); s1 = fmaf(d0.y, wk0.y, s1);
        s1 = fmaf(d0.z, wk0.z, s1); s1 = fmaf(d0.w, wk0.w, s1);
        s1 = fmaf(d1.x, wk1.x, s1); s1 = fmaf(d1.y, wk1.y, s1);
        s1 = fmaf(d1.z, wk1.z, s1); s1 = fmaf(d1.w, wk1.w, s1);
        s1 = fmaf(d2.x, wk2.x, s1); s1 = fmaf(d2.y, wk2.y, s1);
        s1 = fmaf(d2.z, wk2.z, s1); s1 = fmaf(d2.w, wk2.w, s1);
        s1 = fmaf(d3.x, wk3.x, s1); s1 = fmaf(d3.y, wk3.y, s1);
        s1 = fmaf(d3.z, wk3.z, s1); s1 = fmaf(d3.w, wk3.w, s1);

#pragma unroll
        for (int off = 32; off; off >>= 1) {
            s0 += __shfl_xor(s0, off);
            s1 += __shfl_xor(s1, off);
        }
        if (lane == 0) {
            float e0 = expf(s0), e1 = expf(s1);
            if (!(c0 & INVB)) e_out[b * 512 + n0] = e0;
            if (!(c1 & INVB)) e_out[b * 512 + n1] = e1;
            eso[r0]     = make_float2((c0 & SBIT) ? e0 : 0.f, (c0 & OBIT) ? e0 : 0.f);
            eso[r0 + 1] = make_float2((c1 & SBIT) ? e1 : 0.f, (c1 & OBIT) ? e1 : 0.f);
        }
    }
    __syncthreads();

    // ---- compaction of (s|o)-active rows by wave 0 -------------------------
    if (wave == 0) {
        bool pred = (lane < 16) && ((codeL[lane] & (SBIT | OBIT)) != 0) &&
                    !(codeL[lane] & INVB);
        unsigned long long m = __ballot(pred);
        int cnz = __popcll(m);
        if (pred) {
            int pos = __popcll(m & ((1ull << lane) - 1ull));
            cn[pos] = codeL[lane] & 511;
            cw[pos] = eso[lane];
        }
        int cnz8 = (cnz + 7) & ~7;
        if (lane >= 16 && lane < 24) {
            int p = cnz + (lane - 16);
            if (p < cnz8) { cn[p] = 0; cw[p] = make_float2(0.f, 0.f); }
        }
        if (lane == 0) s_cnz8 = cnz8;
    }
    __syncthreads();

    // ---- phase 2: V-weight active rows, 8-deep batches ---------------------
    int cnz8 = s_cnz8;
    const float* Vb = V + (size_t)(b * 512) * HDIM;
    float4 a0 = {0.f, 0.f, 0.f, 0.f};
    float4 a1 = {0.f, 0.f, 0.f, 0.f};
    for (int g = 0; g < cnz8; g += 8) {
        int nn[8]; float2 ww[8];
#pragma unroll
        for (int i = 0; i < 8; ++i) { nn[i] = cn[g + i]; ww[i] = cw[g + i]; }
        float4 v[8];
#pragma unroll
        for (int i = 0; i < 8; ++i)
            v[i] = *((const float4*)(Vb + (size_t)nn[i] * HDIM) + tid);
        __builtin_amdgcn_sched_barrier(0);
#pragma unroll
        for (int i = 0; i < 8; ++i) {
            a0.x = fmaf(ww[i].x, v[i].x, a0.x); a0.y = fmaf(ww[i].x, v[i].y, a0.y);
            a0.z = fmaf(ww[i].x, v[i].z, a0.z); a0.w = fmaf(ww[i].x, v[i].w, a0.w);
            a1.x = fmaf(ww[i].y, v[i].x, a1.x); a1.y = fmaf(ww[i].y, v[i].y, a1.y);
            a1.z = fmaf(ww[i].y, v[i].z, a1.z); a1.w = fmaf(ww[i].y, v[i].w, a1.w);
        }
    }
    *(float4*)(p0 + pbase) = a0;
    *(float4*)(p1 + pbase) = a1;
}

// ---------------- K2: denom + attn_weight + u reduce+normalize --------------
// grid 64 blocks (per b) x 512 threads.
__global__ __launch_bounds__(512) void k_denomredu(const float* __restrict__ e,
                                                   const int* __restrict__ adj,
                                                   const float* __restrict__ p0,
                                                   const float* __restrict__ p1,
                                                   float* __restrict__ w_out,
                                                   float* __restrict__ u0,
                                                   float* __restrict__ u1) {
    __shared__ float red[8];
    int b = blockIdx.x;
    int tid = threadIdx.x;
    int wave = tid >> 6, lane = tid & 63;
    int idx = b * 512 + tid;

    float ev = adj[idx] ? e[idx] : 0.f;
    float t = ev;
#pragma unroll
    for (int off = 32; off; off >>= 1) t += __shfl_xor(t, off);
    if (lane == 0) red[wave] = t;
    __syncthreads();
    float tot = red[0];
#pragma unroll
    for (int i = 1; i < 8; ++i) tot += red[i];
    float inv = 1.f / tot;
    w_out[idx] = ev * inv;

    // reduce SLOTS partials, scale by inv
    const float* p = (tid < 256) ? p0 : p1;
    float* u = (tid < 256) ? u0 : u1;
    int h4 = tid & 255;
    float4 a = {0.f, 0.f, 0.f, 0.f};
#pragma unroll
    for (int s = 0; s < SLOTS; ++s) {
        float4 v = *(const float4*)(p + ((size_t)(s * 64 + b)) * HDIM + h4 * 4);
        a.x += v.x; a.y += v.y; a.z += v.z; a.w += v.w;
    }
    a.x *= inv; a.y *= inv; a.z *= inv; a.w *= inv;
    *(float4*)(u + (size_t)b * HDIM + h4 * 4) = a;
}

// ---------------- K3: split-k GEMM partials: pOut[kc][h][b] -----------------
__global__ __launch_bounds__(256) void k_out(const float* __restrict__ u0,
                                             const float* __restrict__ u1,
                                             const float* __restrict__ Wr0,
                                             const float* __restrict__ Wr1,
                                             float* __restrict__ pOut) {
    __shared__ float lds[64 * 128];
    int tid = threadIdx.x;
    int ht = blockIdx.x >> 4;
    int kc = blockIdx.x & 15;
    const float* usrc = (kc < 8) ? u0 : u1;
    const float* wsrc = (kc < 8) ? Wr0 : Wr1;
    int koff = (kc & 7) * 128;
    int h0 = ht * 64;

    {
        int c4 = tid & 31;
        int r2 = tid >> 5;
#pragma unroll
        for (int i = 0; i < 8; ++i) {
            int row = i * 8 + r2;
            float4 v = *(const float4*)(usrc + (size_t)row * HDIM + koff + c4 * 4);
            *(float4*)&lds[row * 128 + ((c4 ^ (row & 7)) << 2)] = v;
        }
    }
    __syncthreads();

    int b = tid & 63;
    int wu = __builtin_amdgcn_readfirstlane(tid >> 6);
    int hbase = h0 + wu * 16;
    const float* wrow = wsrc + (size_t)hbase * HDIM + koff;

    float acc[16];
#pragma unroll
    for (int j = 0; j < 16; ++j) acc[j] = 0.f;

#pragma unroll 4
    for (int k4 = 0; k4 < 32; ++k4) {
        float4 uv = *(float4*)&lds[b * 128 + ((k4 ^ (b & 7)) << 2)];
#pragma unroll
        for (int j = 0; j < 16; ++j) {
            float4 wv = *(const float4*)(wrow + (size_t)j * HDIM + k4 * 4);
            acc[j] = fmaf(uv.x, wv.x, acc[j]);
            acc[j] = fmaf(uv.y, wv.y, acc[j]);
            acc[j] = fmaf(uv.z, wv.z, acc[j]);
            acc[j] = fmaf(uv.w, wv.w, acc[j]);
        }
    }
#pragma unroll
    for (int j = 0; j < 16; ++j)
        pOut[((size_t)kc * HDIM + hbase + j) * 64 + b] = acc[j];
}

// ---------------- K4: reduce 16 k-chunks -> attn_sum[b][h] ------------------
__global__ __launch_bounds__(256) void k_redout(const float* __restrict__ pOut,
                                                float* __restrict__ out1) {
    int tid = threadIdx.x;
    int b = tid & 63;
    int h = blockIdx.x * 4 + (tid >> 6);
    float acc = 0.f;
#pragma unroll
    for (int kc = 0; kc < 16; ++kc)
        acc += pOut[((size_t)kc * HDIM + h) * 64 + b];
    out1[(size_t)b * HDIM + h] = acc;
}

extern "C" void kernel_launch(void* const* d_in, const int* in_sizes, int n_in,
                              void* d_out, int out_size, void* d_ws, size_t ws_size,
                              hipStream_t stream) {
    const float* Kmat  = (const float*)d_in[1];
    const float* V     = (const float*)d_in[2];
    const int*   adj   = (const int*)d_in[3];
    const int*   smask = (const int*)d_in[4];
    const int*   omask = (const int*)d_in[5];
    const float* Watt  = (const float*)d_in[6];
    const float* Wr0   = (const float*)d_in[8];
    const float* Wr1   = (const float*)d_in[9];
    float* out = (float*)d_out;
    float* ws  = (float*)d_ws;

    // ws layout (float offsets)
    float* e    = ws;                    //  64*512              = 32768
    int*   idxK = (int*)(ws + 32768);    //  64*512              = 32768
    int*   cKp  = (int*)(ws + 65536);    //  64 (pad 128)
    float* p0   = ws + 65664;            //  SLOTS*64*1024       = 1310720
    float* p1   = ws + 1376384;          //  SLOTS*64*1024       = 1310720
    float* u0   = ws + 2687104;          //  64*1024             = 65536
    float* u1   = ws + 2752640;          //  64*1024             = 65536
    float* pOut = ws + 2818176;          //  16*1024*64          = 1048576
    const float* Wk = Watt + HDIM;       // second half of W_att

    k_prep     <<<          64, 512, 0, stream>>>(adj, smask, omask, idxK, cKp);
    k_fusedA   <<< 64 * SLOTS, 256, 0, stream>>>(Kmat, V, Wk, idxK, cKp, e, p0, p1);
    k_denomredu<<<          64, 512, 0, stream>>>(e, adj, p0, p1, out, u0, u1);
    k_out      <<<         256, 256, 0, stream>>>(u0, u1, Wr0, Wr1, pOut);
    k_redout   <<<         256, 256, 0, stream>>>(pOut, out + 32768);
}